// Round 1
// baseline (388.622 us; speedup 1.0000x reference)
//
#include <hip/hip_runtime.h>

// QWK loss, MI355X.
// Stage 1: argmax over 8 logits per position + masked 8x8 confusion histogram
//          (exact integer counts; LDS per-block histogram -> 64 global atomics/block).
// Stage 2: single-thread double-precision finalization (counts < 2^24, exact).

#define NCATS 8
#define NBINS 64

__global__ __launch_bounds__(256) void qwk_hist_kernel(
    const float* __restrict__ logits,
    const int* __restrict__ targets,
    unsigned int* __restrict__ hist,
    int npos)
{
    __shared__ unsigned int lh[NBINS];
    const int tid = threadIdx.x;
    if (tid < NBINS) lh[tid] = 0u;
    __syncthreads();

    const int stride = gridDim.x * blockDim.x;
    for (int pos = blockIdx.x * blockDim.x + tid; pos < npos; pos += stride) {
        const float4* lp = (const float4*)(logits + (size_t)pos * NCATS);
        float4 a = lp[0];
        float4 b = lp[1];
        float v0 = a.x, v1 = a.y, v2 = a.z, v3 = a.w;
        float v4 = b.x, v5 = b.y, v6 = b.z, v7 = b.w;
        // argmax with first-occurrence tie-break (strict >), matches np/jnp argmax
        int best = 0; float bv = v0;
        if (v1 > bv) { bv = v1; best = 1; }
        if (v2 > bv) { bv = v2; best = 2; }
        if (v3 > bv) { bv = v3; best = 3; }
        if (v4 > bv) { bv = v4; best = 4; }
        if (v5 > bv) { bv = v5; best = 5; }
        if (v6 > bv) { bv = v6; best = 6; }
        if (v7 > bv) { bv = v7; best = 7; }
        int t = targets[pos];
        if (t > 0) atomicAdd(&lh[t * NCATS + best], 1u);
    }
    __syncthreads();

    if (tid < NBINS) {
        unsigned int c = lh[tid];
        if (c) atomicAdd(&hist[tid], c);
    }
}

__global__ void qwk_final_kernel(const unsigned int* __restrict__ hist,
                                 float* __restrict__ out)
{
    if (threadIdx.x == 0 && blockIdx.x == 0) {
        double cm[NBINS];
        double n = 0.0;
        #pragma unroll
        for (int i = 0; i < NBINS; ++i) { cm[i] = (double)hist[i]; n += cm[i]; }

        double loss;
        if (n == 0.0) {
            loss = 0.0;  // n==0 -> qwk=1 -> loss 0
        } else {
            double inv = 1.0 / n;
            double mt[NCATS], mp[NCATS];
            #pragma unroll
            for (int i = 0; i < NCATS; ++i) { mt[i] = 0.0; mp[i] = 0.0; }
            #pragma unroll
            for (int i = 0; i < NCATS; ++i) {
                #pragma unroll
                for (int j = 0; j < NCATS; ++j) {
                    double c = cm[i * NCATS + j] * inv;
                    mt[i] += c;
                    mp[j] += c;
                }
            }
            double num = 0.0, den = 0.0;
            #pragma unroll
            for (int i = 0; i < NCATS; ++i) {
                #pragma unroll
                for (int j = 0; j < NCATS; ++j) {
                    double d = (double)(i - j);
                    double w = 1.0 - d * d / 49.0;   // (NCATS-1)^2 = 49
                    num += w * (cm[i * NCATS + j] * inv);
                    den += w * (mt[i] * mp[j]);
                }
            }
            double qwk = (den == 0.0) ? 0.0 : (num / den);
            loss = 1.0 - qwk;
        }
        out[0] = (float)loss;
    }
}

extern "C" void kernel_launch(void* const* d_in, const int* in_sizes, int n_in,
                              void* d_out, int out_size, void* d_ws, size_t ws_size,
                              hipStream_t stream)
{
    const float* logits = (const float*)d_in[0];
    const int* targets = (const int*)d_in[1];
    float* out = (float*)d_out;
    unsigned int* hist = (unsigned int*)d_ws;

    const int npos = in_sizes[0] / NCATS;  // = BATCH*SEQ

    // d_ws is poisoned to 0xAA before every call — zero the histogram bins.
    hipMemsetAsync(hist, 0, NBINS * sizeof(unsigned int), stream);

    const int threads = 256;
    const int blocks = 1024;  // grid-stride; ~32 positions/thread at 8.4M
    qwk_hist_kernel<<<blocks, threads, 0, stream>>>(logits, targets, hist, npos);
    qwk_final_kernel<<<1, 64, 0, stream>>>(hist, out);
}

// Round 2
// 388.021 us; speedup vs baseline: 1.0016x; 1.0016x over previous
//
#include <hip/hip_runtime.h>

// QWK loss, MI355X. 302 MB input read -> memory-bound, floor ~46 us @6.6 TB/s.
// Stage 1: argmax over 8 logits per position + masked per-block 8x8 histogram
//          in LDS; each block OVERWRITES its private 64-uint slice of d_ws
//          (no zeroing / no global atomics needed).
// Stage 2: single-block reduce of 2048 partial histograms + double-precision
//          kappa finalization (counts < 2^24 are exact in f64).

#define NCATS 8
#define NBINS 64
#define NPART 2048          // blocks in stage 1; 2048*4 waves = 32 waves/CU

__global__ __launch_bounds__(256) void qwk_hist_kernel(
    const float* __restrict__ logits,
    const int* __restrict__ targets,
    unsigned int* __restrict__ part,   // [NPART][NBINS]
    int npos)
{
    __shared__ unsigned int lh[NBINS];
    const int tid = threadIdx.x;
    if (tid < NBINS) lh[tid] = 0u;
    __syncthreads();

    const int stride = gridDim.x * blockDim.x;
    for (int pos = blockIdx.x * blockDim.x + tid; pos < npos; pos += stride) {
        const float4* lp = (const float4*)(logits + (size_t)pos * NCATS);
        float4 a = lp[0];
        float4 b = lp[1];
        // argmax with first-occurrence tie-break (strict >), matches jnp argmax
        int best = 0; float bv = a.x;
        if (a.y > bv) { bv = a.y; best = 1; }
        if (a.z > bv) { bv = a.z; best = 2; }
        if (a.w > bv) { bv = a.w; best = 3; }
        if (b.x > bv) { bv = b.x; best = 4; }
        if (b.y > bv) { bv = b.y; best = 5; }
        if (b.z > bv) { bv = b.z; best = 6; }
        if (b.w > bv) { bv = b.w; best = 7; }
        int t = targets[pos];
        if (t > 0) atomicAdd(&lh[t * NCATS + best], 1u);
    }
    __syncthreads();

    if (tid < NBINS) part[blockIdx.x * NBINS + tid] = lh[tid];
}

__global__ __launch_bounds__(256) void qwk_final_kernel(
    const unsigned int* __restrict__ part,
    float* __restrict__ out)
{
    __shared__ unsigned int sums[256];
    __shared__ double cm[NBINS];
    const int t = threadIdx.x;
    const int bin = t & 63;
    const int stripe = t >> 6;                 // 4 stripes of NPART/4 blocks
    const int per = NPART / 4;

    unsigned int s = 0;
    #pragma unroll 8
    for (int i = 0; i < per; ++i)
        s += part[(size_t)(stripe * per + i) * NBINS + bin];
    sums[t] = s;
    __syncthreads();

    if (t < NBINS)
        cm[t] = (double)(sums[t] + sums[t + 64] + sums[t + 128] + sums[t + 192]);
    __syncthreads();

    if (t == 0) {
        double n = 0.0;
        #pragma unroll
        for (int i = 0; i < NBINS; ++i) n += cm[i];

        double loss;
        if (n == 0.0) {
            loss = 0.0;  // n==0 -> qwk=1 -> loss 0
        } else {
            double inv = 1.0 / n;
            double mt[NCATS], mp[NCATS];
            #pragma unroll
            for (int i = 0; i < NCATS; ++i) { mt[i] = 0.0; mp[i] = 0.0; }
            #pragma unroll
            for (int i = 0; i < NCATS; ++i) {
                #pragma unroll
                for (int j = 0; j < NCATS; ++j) {
                    double c = cm[i * NCATS + j] * inv;
                    mt[i] += c;
                    mp[j] += c;
                }
            }
            double num = 0.0, den = 0.0;
            #pragma unroll
            for (int i = 0; i < NCATS; ++i) {
                #pragma unroll
                for (int j = 0; j < NCATS; ++j) {
                    double d = (double)(i - j);
                    double w = 1.0 - d * d / 49.0;   // (NCATS-1)^2 = 49
                    num += w * (cm[i * NCATS + j] * inv);
                    den += w * (mt[i] * mp[j]);
                }
            }
            double qwk = (den == 0.0) ? 0.0 : (num / den);
            loss = 1.0 - qwk;
        }
        out[0] = (float)loss;
    }
}

extern "C" void kernel_launch(void* const* d_in, const int* in_sizes, int n_in,
                              void* d_out, int out_size, void* d_ws, size_t ws_size,
                              hipStream_t stream)
{
    const float* logits = (const float*)d_in[0];
    const int* targets = (const int*)d_in[1];
    float* out = (float*)d_out;
    unsigned int* part = (unsigned int*)d_ws;   // NPART*NBINS uints, fully overwritten

    const int npos = in_sizes[0] / NCATS;       // = BATCH*SEQ

    qwk_hist_kernel<<<NPART, 256, 0, stream>>>(logits, targets, part, npos);
    qwk_final_kernel<<<1, 256, 0, stream>>>(part, out);
}